// Round 4
// baseline (346.716 us; speedup 1.0000x reference)
//
#include <hip/hip_runtime.h>
#include <cstddef>
#include <cstdint>

// Problem constants (fixed by setup_inputs)
constexpr int B_SEG   = 4;
constexpr int N_C     = 4096;    // coarse points per batch
constexpr int M_F     = 16384;   // fine points per batch
constexpr int CIN     = 384;
constexpr int COUT    = 192;
constexpr int MT      = B_SEG * N_C;   // 16384 coarse rows
constexpr int MF      = B_SEG * M_F;   // 65536 fine rows
constexpr float LN_EPS = 1e-5f;

constexpr int GRID  = 12;              // KNN cell grid per axis
constexpr int NCELL = GRID * GRID * GRID;   // 1728

typedef __bf16 bf16x8 __attribute__((ext_vector_type(8)));
typedef __bf16 bf16x4 __attribute__((ext_vector_type(4)));
typedef float  f32x4  __attribute__((ext_vector_type(4)));

// ---------------------------------------------------------------------------
// K0: one-time prep — transpose+convert weights to bf16 [n][k] layout.
// ---------------------------------------------------------------------------
__global__ __launch_bounds__(256) void k0_prep(
    const float* __restrict__ w2, const float* __restrict__ w1,
    __bf16* __restrict__ wt2, __bf16* __restrict__ wt1)
{
  int e = blockIdx.x * 256 + threadIdx.x;
  if (e < CIN * COUT) {                       // w2: [384][192] -> wt2 [192][384]
    int k = e / COUT, n = e % COUT;
    wt2[(size_t)n * CIN + k] = (__bf16)w2[e];
  }
  e -= CIN * COUT;
  if (e >= 0 && e < COUT * COUT) {            // w1: [192][192] -> wt1 [192][192]
    int k = e / COUT, n = e % COUT;
    wt1[(size_t)n * COUT + k] = (__bf16)w1[e];
  }
}

// ---------------------------------------------------------------------------
// K2s: counting-sort each batch's src points into 12^3 cells.
// Grid = 4 blocks (one per batch) x 256 threads.
// Output: psort[b][4096] = {x,y,z,bitcast(orig_j)}, cstart[b][1729].
// ---------------------------------------------------------------------------
__global__ __launch_bounds__(256) void k2s_sort(
    const float* __restrict__ xyz, float4* __restrict__ psort,
    int* __restrict__ cstart)
{
  __shared__ int hist[1792];
  __shared__ int base[1792];
  __shared__ int wtot[4];
  const int tid = threadIdx.x;
  const int b   = blockIdx.x;
#pragma unroll
  for (int i = 0; i < 7; ++i) hist[tid + 256 * i] = 0;
  __syncthreads();

  float px[16], py[16], pz[16];
  int   pc[16];
  const float* src = xyz + (size_t)b * N_C * 3;
#pragma unroll
  for (int k = 0; k < 16; ++k) {
    int j = tid + 256 * k;
    float x = src[3 * j], y = src[3 * j + 1], z = src[3 * j + 2];
    int cx = min(GRID - 1, max(0, (int)(x * (float)GRID)));
    int cy = min(GRID - 1, max(0, (int)(y * (float)GRID)));
    int cz = min(GRID - 1, max(0, (int)(z * (float)GRID)));
    int c  = (cx * GRID + cy) * GRID + cz;
    px[k] = x; py[k] = y; pz[k] = z; pc[k] = c;
    atomicAdd(&hist[c], 1);
  }
  __syncthreads();

  // exclusive prefix over 1792 cells: 7 per thread + wave scan + wave offsets
  int loc[7], s = 0;
#pragma unroll
  for (int i = 0; i < 7; ++i) { loc[i] = hist[tid * 7 + i]; s += loc[i]; }
  const int lane = tid & 63, wv = tid >> 6;
  int incl = s;
#pragma unroll
  for (int off = 1; off < 64; off <<= 1) {
    int n = __shfl_up(incl, off);
    if (lane >= off) incl += n;
  }
  if (lane == 63) wtot[wv] = incl;
  __syncthreads();
  int wbase = 0;
  for (int w = 0; w < 4; ++w) if (w < wv) wbase += wtot[w];
  int run = wbase + (incl - s);
#pragma unroll
  for (int i = 0; i < 7; ++i) { base[tid * 7 + i] = run; run += loc[i]; }
  __syncthreads();

  // cell_start output (1729 entries; base[1728] == 4096 since pad cells empty)
#pragma unroll
  for (int i = 0; i < 7; ++i) {
    int idx = tid + 256 * i;
    if (idx < NCELL + 1) cstart[(size_t)b * (NCELL + 1) + idx] = base[idx];
  }
  // cursor = copy of base
#pragma unroll
  for (int i = 0; i < 7; ++i) hist[tid + 256 * i] = base[tid + 256 * i];
  __syncthreads();
#pragma unroll
  for (int k = 0; k < 16; ++k) {
    int pos = atomicAdd(&hist[pc[k]], 1);
    psort[(size_t)b * N_C + pos] =
        make_float4(px[k], py[k], pz[k], __int_as_float(tid + 256 * k));
  }
}

// ---------------------------------------------------------------------------
// K2: exact 3-NN via cell list. One thread per dst point; whole batch's
// sorted points staged in LDS (61 KB). Guarantee loop: expand search ring
// until 3rd-best d2 < (margin-to-searched-boundary - eps)^2.
// Distance rounding replicates the reference exactly; (d2, orig_j)
// lexicographic insert == stable top_k tie-break.
// ---------------------------------------------------------------------------
__global__ __launch_bounds__(256) void k2_knn(
    const float4* __restrict__ psort, const int* __restrict__ cstart,
    const float* __restrict__ sxyz, int* __restrict__ knn_i,
    float* __restrict__ knn_w)
{
  __shared__ float Px[N_C], Py[N_C], Pz[N_C];       // 48 KB
  __shared__ unsigned short Pi[N_C];                // 8 KB
  __shared__ unsigned short CS[NCELL + 2];          // 3.46 KB
  const int tid = threadIdx.x;
  const int blk = blockIdx.x;
  const int b   = blk >> 6;                         // 64 blocks per batch

#pragma unroll
  for (int i = 0; i < 16; ++i) {
    int idx = tid + 256 * i;
    float4 q = psort[(size_t)b * N_C + idx];
    Px[idx] = q.x; Py[idx] = q.y; Pz[idx] = q.z;
    Pi[idx] = (unsigned short)__float_as_int(q.w);
  }
#pragma unroll
  for (int i = 0; i < 7; ++i) {
    int idx = tid + 256 * i;
    if (idx < NCELL + 1)
      CS[idx] = (unsigned short)cstart[(size_t)b * (NCELL + 1) + idx];
  }
  const int dst = blk * 256 + tid;
  const float px = sxyz[(size_t)dst * 3 + 0];
  const float py = sxyz[(size_t)dst * 3 + 1];
  const float pz = sxyz[(size_t)dst * 3 + 2];
  __syncthreads();

  const int cx = min(GRID - 1, max(0, (int)(px * (float)GRID)));
  const int cy = min(GRID - 1, max(0, (int)(py * (float)GRID)));
  const int cz = min(GRID - 1, max(0, (int)(pz * (float)GRID)));

  float t0 = 1e30f, t1 = 1e30f, t2 = 1e30f;
  int   j0 = 0x7fffffff, j1 = 0x7fffffff, j2 = 0x7fffffff;

  auto scanRange = [&](int ks, int ke) {
    for (int k = ks; k < ke; ++k) {
      float dx = __fsub_rn(px, Px[k]);
      float dy = __fsub_rn(py, Py[k]);
      float dz = __fsub_rn(pz, Pz[k]);
      float d2 = __fadd_rn(__fadd_rn(__fmul_rn(dx, dx), __fmul_rn(dy, dy)),
                           __fmul_rn(dz, dz));
      int j = (int)Pi[k];
      bool lt2 = (d2 < t2) || (d2 == t2 && j < j2);
      if (lt2) {
        bool lt1 = (d2 < t1) || (d2 == t1 && j < j1);
        if (lt1) {
          t2 = t1; j2 = j1;
          bool lt0 = (d2 < t0) || (d2 == t0 && j < j0);
          if (lt0) { t1 = t0; j1 = j0; t0 = d2; j0 = j; }
          else     { t1 = d2; j1 = j; }
        } else { t2 = d2; j2 = j; }
      }
    }
  };

  const float h = 1.0f / (float)GRID;
  for (int r = 1; r <= GRID; ++r) {
    const int xlo = max(cx - r, 0), xhi = min(cx + r, GRID - 1);
    const int ylo = max(cy - r, 0), yhi = min(cy + r, GRID - 1);
    const int zlo = max(cz - r, 0), zhi = min(cz + r, GRID - 1);
    for (int x = xlo; x <= xhi; ++x) {
      for (int y = ylo; y <= yhi; ++y) {
        if (r > 1) {
          int ax = x - cx; ax = ax < 0 ? -ax : ax;
          int ay = y - cy; ay = ay < 0 ? -ay : ay;
          if (ax < r && ay < r) {
            // interior (x,y): only z = cz +/- r belong to this shell
            int zl = cz - r, zh = cz + r;
            int cb = (x * GRID + y) * GRID;
            if (zl >= 0)        scanRange(CS[cb + zl], CS[cb + zl + 1]);
            if (zh <= GRID - 1) scanRange(CS[cb + zh], CS[cb + zh + 1]);
            continue;
          }
        }
        int cb = (x * GRID + y) * GRID;
        scanRange(CS[cb + zlo], CS[cb + zhi + 1]);   // contiguous z-run
      }
    }
    // guarantee margin: distance from p to searched-block boundary
    float m = 1e30f;
    if (cx - r > 0)        m = fminf(m, px - (float)(cx - r) * h);
    if (cx + r < GRID - 1) m = fminf(m, (float)(cx + r + 1) * h - px);
    if (cy - r > 0)        m = fminf(m, py - (float)(cy - r) * h);
    if (cy + r < GRID - 1) m = fminf(m, (float)(cy + r + 1) * h - py);
    if (cz - r > 0)        m = fminf(m, pz - (float)(cz - r) * h);
    if (cz + r < GRID - 1) m = fminf(m, (float)(cz + r + 1) * h - pz);
    float ma = m - 1e-5f;
    if (t2 < ma * ma) break;
  }

  float d0 = sqrtf(t0), d1 = sqrtf(t1), d2s = sqrtf(t2);
  float r0 = 1.f / (d0 + 1e-8f);
  float r1 = 1.f / (d1 + 1e-8f);
  float r2 = 1.f / (d2s + 1e-8f);
  float inv = 1.f / (r0 + r1 + r2);
  knn_i[(size_t)dst * 3 + 0] = b * N_C + j0;
  knn_i[(size_t)dst * 3 + 1] = b * N_C + j1;
  knn_i[(size_t)dst * 3 + 2] = b * N_C + j2;
  knn_w[(size_t)dst * 3 + 0] = r0 * inv;
  knn_w[(size_t)dst * 3 + 1] = r1 * inv;
  knn_w[(size_t)dst * 3 + 2] = r2 * inv;
}

// ---------------------------------------------------------------------------
// K1: h = LN(feats) @ w2 + b2      [16384 x 384] x [384 x 192]
// 16 rows/block, grid 1024. 4 waves each own 3 of the 12 col-blocks.
// LDS 12.5 KB, acc[3] -> low VGPR -> 4+ blocks/CU.
// ---------------------------------------------------------------------------
__global__ __launch_bounds__(256) void k1_ln_gemm(
    const float* __restrict__ feats, const float* __restrict__ ln_g,
    const float* __restrict__ ln_b, const __bf16* __restrict__ wt2,
    const float* __restrict__ b2, float* __restrict__ h)
{
  __shared__ __bf16 As[16][CIN + 8];
  const int tid = threadIdx.x;
  const int blk = blockIdx.x;

  // ---- LN: 16 threads/row, 6 float4 each ----
  {
    const int r = tid >> 4, q = tid & 15;
    const float* frow = feats + (size_t)(blk * 16 + r) * CIN;
    float4 v[6];
    float sum = 0.f, sumsq = 0.f;
#pragma unroll
    for (int i = 0; i < 6; ++i) {
      float4 t = *(const float4*)(frow + (q + 16 * i) * 4);
      v[i] = t;
      sum   += (t.x + t.y) + (t.z + t.w);
      sumsq += (t.x * t.x + t.y * t.y) + (t.z * t.z + t.w * t.w);
    }
#pragma unroll
    for (int off = 1; off < 16; off <<= 1) {
      sum   += __shfl_xor(sum, off);
      sumsq += __shfl_xor(sumsq, off);
    }
    float mean = sum * (1.f / CIN);
    float var  = sumsq * (1.f / CIN) - mean * mean;
    if (var < 0.f) var = 0.f;
    float rs = rsqrtf(var + LN_EPS);
#pragma unroll
    for (int i = 0; i < 6; ++i) {
      float4 g4 = *(const float4*)(ln_g + (q + 16 * i) * 4);
      float4 b4 = *(const float4*)(ln_b + (q + 16 * i) * 4);
      bf16x4 o;
      o[0] = (__bf16)((v[i].x - mean) * rs * g4.x + b4.x);
      o[1] = (__bf16)((v[i].y - mean) * rs * g4.y + b4.y);
      o[2] = (__bf16)((v[i].z - mean) * rs * g4.z + b4.z);
      o[3] = (__bf16)((v[i].w - mean) * rs * g4.w + b4.w);
      *(bf16x4*)&As[r][(q + 16 * i) * 4] = o;
    }
  }
  __syncthreads();

  // ---- MFMA: wave w handles col-blocks w*3 .. w*3+2 ----
  const int w = tid >> 6, lane = tid & 63, m = lane & 15, half = lane >> 4;
  f32x4 acc[3];
#pragma unroll
  for (int t = 0; t < 3; ++t) acc[t] = (f32x4){0.f, 0.f, 0.f, 0.f};

  const __bf16* Arow = &As[m][half * 8];
#pragma unroll
  for (int ch = 0; ch < 12; ++ch) {
    bf16x8 a = *(const bf16x8*)(Arow + ch * 32);
#pragma unroll
    for (int t = 0; t < 3; ++t) {
      const __bf16* bp = wt2 + (size_t)(16 * (w * 3 + t) + m) * CIN +
                         half * 8 + ch * 32;
      bf16x8 b = *(const bf16x8*)bp;
      acc[t] = __builtin_amdgcn_mfma_f32_16x16x32_bf16(a, b, acc[t], 0, 0, 0);
    }
  }

  // ---- Epilogue: D layout col=lane&15, row=(lane>>4)*4+reg ----
  const int r0 = blk * 16 + half * 4;
#pragma unroll
  for (int t = 0; t < 3; ++t) {
    int col = 16 * (w * 3 + t) + m;
    float bv = b2[col];
#pragma unroll
    for (int reg = 0; reg < 4; ++reg)
      h[(size_t)(r0 + reg) * COUT + col] = acc[t][reg] + bv;
  }
}

// ---------------------------------------------------------------------------
// K3: out = LN(support_feats) @ w1 + b1 + interp(h)   [65536 x 192]
// 16 rows/block, grid 4096; 3-NN gather fused in epilogue.
// ---------------------------------------------------------------------------
__global__ __launch_bounds__(256) void k3_ln_gemm_interp(
    const float* __restrict__ sfeats, const float* __restrict__ ln_g,
    const float* __restrict__ ln_b, const __bf16* __restrict__ wt1,
    const float* __restrict__ b1, const float* __restrict__ h,
    const int* __restrict__ knn_i, const float* __restrict__ knn_w,
    float* __restrict__ out)
{
  __shared__ __bf16 As[16][COUT + 8];
  const int tid = threadIdx.x;
  const int blk = blockIdx.x;

  // ---- LN: 16 threads/row, 3 float4 each ----
  {
    const int r = tid >> 4, q = tid & 15;
    const float* frow = sfeats + (size_t)(blk * 16 + r) * COUT;
    float4 v[3];
    float sum = 0.f, sumsq = 0.f;
#pragma unroll
    for (int i = 0; i < 3; ++i) {
      float4 t = *(const float4*)(frow + (q + 16 * i) * 4);
      v[i] = t;
      sum   += (t.x + t.y) + (t.z + t.w);
      sumsq += (t.x * t.x + t.y * t.y) + (t.z * t.z + t.w * t.w);
    }
#pragma unroll
    for (int off = 1; off < 16; off <<= 1) {
      sum   += __shfl_xor(sum, off);
      sumsq += __shfl_xor(sumsq, off);
    }
    float mean = sum * (1.f / COUT);
    float var  = sumsq * (1.f / COUT) - mean * mean;
    if (var < 0.f) var = 0.f;
    float rs = rsqrtf(var + LN_EPS);
#pragma unroll
    for (int i = 0; i < 3; ++i) {
      float4 g4 = *(const float4*)(ln_g + (q + 16 * i) * 4);
      float4 b4 = *(const float4*)(ln_b + (q + 16 * i) * 4);
      bf16x4 o;
      o[0] = (__bf16)((v[i].x - mean) * rs * g4.x + b4.x);
      o[1] = (__bf16)((v[i].y - mean) * rs * g4.y + b4.y);
      o[2] = (__bf16)((v[i].z - mean) * rs * g4.z + b4.z);
      o[3] = (__bf16)((v[i].w - mean) * rs * g4.w + b4.w);
      *(bf16x4*)&As[r][(q + 16 * i) * 4] = o;
    }
  }
  __syncthreads();

  // ---- MFMA: wave w handles col-blocks w*3 .. w*3+2 ----
  const int w = tid >> 6, lane = tid & 63, m = lane & 15, half = lane >> 4;
  f32x4 acc[3];
#pragma unroll
  for (int t = 0; t < 3; ++t) acc[t] = (f32x4){0.f, 0.f, 0.f, 0.f};

  const __bf16* Arow = &As[m][half * 8];
#pragma unroll
  for (int ch = 0; ch < 6; ++ch) {
    bf16x8 a = *(const bf16x8*)(Arow + ch * 32);
#pragma unroll
    for (int t = 0; t < 3; ++t) {
      const __bf16* bp = wt1 + (size_t)(16 * (w * 3 + t) + m) * COUT +
                         half * 8 + ch * 32;
      bf16x8 b = *(const bf16x8*)bp;
      acc[t] = __builtin_amdgcn_mfma_f32_16x16x32_bf16(a, b, acc[t], 0, 0, 0);
    }
  }

  // ---- Epilogue: bias + 3-NN inverse-distance gather from h ----
  const int r0 = blk * 16 + half * 4;
#pragma unroll
  for (int reg = 0; reg < 4; ++reg) {
    const int R = r0 + reg;
    int   i0 = knn_i[(size_t)R * 3 + 0];
    int   i1 = knn_i[(size_t)R * 3 + 1];
    int   i2 = knn_i[(size_t)R * 3 + 2];
    float w0 = knn_w[(size_t)R * 3 + 0];
    float w1v = knn_w[(size_t)R * 3 + 1];
    float w2v = knn_w[(size_t)R * 3 + 2];
    const float* h0 = h + (size_t)i0 * COUT;
    const float* h1 = h + (size_t)i1 * COUT;
    const float* h2 = h + (size_t)i2 * COUT;
    float* orow = out + (size_t)R * COUT;
#pragma unroll
    for (int t = 0; t < 3; ++t) {
      int col = 16 * (w * 3 + t) + m;
      orow[col] = acc[t][reg] + b1[col] +
                  w0 * h0[col] + w1v * h1[col] + w2v * h2[col];
    }
  }
}

// ---------------------------------------------------------------------------
// K4: passthrough outputs — support_xyz copy + support_offset as float
// ---------------------------------------------------------------------------
__global__ __launch_bounds__(256) void k4_tail(
    const float* __restrict__ sxyz, const int* __restrict__ soff,
    float* __restrict__ out_tail)
{
  const int t = blockIdx.x * 256 + threadIdx.x;
  if (t < MF * 3) out_tail[t] = sxyz[t];
  if (t < B_SEG) out_tail[MF * 3 + t] = (float)soff[t];
}

// ---------------------------------------------------------------------------
extern "C" void kernel_launch(void* const* d_in, const int* in_sizes, int n_in,
                              void* d_out, int out_size, void* d_ws, size_t ws_size,
                              hipStream_t stream)
{
  const float* feats  = (const float*)d_in[0];
  const float* xyz    = (const float*)d_in[1];
  const float* sxyz   = (const float*)d_in[2];
  const float* sfeats = (const float*)d_in[3];
  const int*   soff   = (const int*)d_in[5];
  const float* ln1_g  = (const float*)d_in[6];
  const float* ln1_b  = (const float*)d_in[7];
  const float* w1     = (const float*)d_in[8];
  const float* b1     = (const float*)d_in[9];
  const float* ln2_g  = (const float*)d_in[10];
  const float* ln2_b  = (const float*)d_in[11];
  const float* w2     = (const float*)d_in[12];
  const float* b2     = (const float*)d_in[13];
  float* out = (float*)d_out;

  // workspace layout (16B-aligned sections)
  float*  h      = (float*)d_ws;                       // 16384*192 f32 (12.6 MB)
  int*    knn_i  = (int*)(h + (size_t)MT * COUT);      // 65536*3
  float*  knn_w  = (float*)(knn_i + (size_t)MF * 3);   // 65536*3
  float4* psort  = (float4*)(knn_w + (size_t)MF * 3);  // 4*4096 float4 (256 KB)
  int*    cstart = (int*)(psort + (size_t)B_SEG * N_C);// 4*1729
  __bf16* wt2    = (__bf16*)(cstart + (size_t)B_SEG * (NCELL + 1) + 3); // pad->16B
  __bf16* wt1    = wt2 + (size_t)COUT * CIN;

  k0_prep<<<432, 256, 0, stream>>>(w2, w1, wt2, wt1);
  k2s_sort<<<B_SEG, 256, 0, stream>>>(xyz, psort, cstart);
  k1_ln_gemm<<<MT / 16, 256, 0, stream>>>(feats, ln2_g, ln2_b, wt2, b2, h);
  k2_knn<<<MF / 256, 256, 0, stream>>>(psort, cstart, sxyz, knn_i, knn_w);
  k3_ln_gemm_interp<<<MF / 16, 256, 0, stream>>>(sfeats, ln1_g, ln1_b, wt1, b1,
                                                 h, knn_i, knn_w, out);
  k4_tail<<<(MF * 3) / 256, 256, 0, stream>>>(sxyz, soff, out + (size_t)MF * COUT);
}